// Round 14
// baseline (121.025 us; speedup 1.0000x reference)
//
#include <hip/hip_runtime.h>
#include <stdint.h>

#define SEQ 2048

typedef __attribute__((ext_vector_type(8))) short bf16x8;
typedef __attribute__((ext_vector_type(4))) float f32x4;
typedef __attribute__((ext_vector_type(4))) int i32x4;

typedef const __attribute__((address_space(1))) unsigned int GVT;
typedef __attribute__((address_space(3))) unsigned int LVT;

static __device__ __forceinline__ unsigned short f2bf(float f) {
  unsigned u = __builtin_bit_cast(unsigned, f);
  u += 0x7fffu + ((u >> 16) & 1u);
  return (unsigned short)(u >> 16);
}

static __device__ __forceinline__ unsigned pk_bf16(float lo, float hi) {
  unsigned r;
  asm("v_cvt_pk_bf16_f32 %0, %1, %2" : "=v"(r) : "v"(lo), "v"(hi));
  return r;
}

// one kernel converts x, w_qkv, w_proj (saves 2 launch overheads)
__global__ __launch_bounds__(256) void cvt3_kernel(
    const float* __restrict__ s0, unsigned short* __restrict__ d0, int n0,
    const float* __restrict__ s1, unsigned short* __restrict__ d1, int n1,
    const float* __restrict__ s2, unsigned short* __restrict__ d2, int n2) {
  int i = blockIdx.x * 256 + threadIdx.x;
  const int stride = gridDim.x * 256;
  const int total = n0 + n1 + n2;
  for (; i < total; i += stride) {
    const float* s;
    unsigned short* d;
    int k;
    if (i < n0) { s = s0; d = d0; k = i; }
    else if (i < n0 + n1) { s = s1; d = d1; k = i - n0; }
    else { s = s2; d = d2; k = i - n0 - n1; }
    float4 v = reinterpret_cast<const float4*>(s)[k];
    ushort4 o;
    o.x = f2bf(v.x); o.y = f2bf(v.y); o.z = f2bf(v.z); o.w = f2bf(v.w);
    reinterpret_cast<ushort4*>(d)[k] = o;
  }
}

// ---------------- QKV GEMM: C[4096][3072] = Xbf @ Wqkv^T, scatter to q/k/vt ----------
// q: [32][2048][64] (pre-scaled by SCALE*log2e); k: [32][2048][64]; vt: [32][64][2048]
__global__ __launch_bounds__(256, 3) void gemm_qkv_kernel(
    const unsigned short* __restrict__ A,    // [4096][1024] bf16
    const unsigned short* __restrict__ Bt,   // [3072][1024] bf16
    const float* __restrict__ bias,          // [3072]
    unsigned short* __restrict__ qb,
    unsigned short* __restrict__ kbuf,
    unsigned short* __restrict__ vtbuf) {
  __shared__ __align__(16) unsigned short As[2][128 * 32];
  __shared__ __align__(16) unsigned short Bs[2][128 * 32];
  const int tid = threadIdx.x;
  const int lane = tid & 63;
  const int wid = tid >> 6;
  const int wr = wid >> 1, wc = wid & 1;
  // XCD-bijective swizzle: 768 blocks, 768/8 = 96 per XCD (4 bm-rows each)
  const int lin = blockIdx.y * 24 + blockIdx.x;
  const int wg = (lin & 7) * 96 + (lin >> 3);
  const int bm = wg / 24, bn = wg % 24;
  const int lr = lane & 15, hg = lane >> 4;

  f32x4 acc[4][4] = {};

  const int r0 = tid >> 2;                 // staging row
  const int c0 = (tid & 3) * 8;            // staging col (elements)

  auto STAGE = [&](int b, int kt) {
    const unsigned short* ga0 = A + (size_t)(bm * 128 + r0) * 1024 + kt * 32 + c0;
    const unsigned short* ga1 = A + (size_t)(bm * 128 + r0 + 64) * 1024 + kt * 32 + c0;
    const unsigned short* gb0 = Bt + (size_t)(bn * 128 + r0) * 1024 + kt * 32 + c0;
    const unsigned short* gb1 = Bt + (size_t)(bn * 128 + r0 + 64) * 1024 + kt * 32 + c0;
    __builtin_amdgcn_global_load_lds((GVT*)ga0, (LVT*)&As[b][tid * 8], 16, 0, 0);
    __builtin_amdgcn_global_load_lds((GVT*)ga1, (LVT*)&As[b][(tid + 256) * 8], 16, 0, 0);
    __builtin_amdgcn_global_load_lds((GVT*)gb0, (LVT*)&Bs[b][tid * 8], 16, 0, 0);
    __builtin_amdgcn_global_load_lds((GVT*)gb1, (LVT*)&Bs[b][(tid + 256) * 8], 16, 0, 0);
  };

  STAGE(0, 0);
  int cur = 0;
  for (int kt = 0; kt < 32; ++kt) {
    __syncthreads();                       // buf[cur] staged; prev reads done
    if (kt + 1 < 32) STAGE(cur ^ 1, kt + 1);
    bf16x8 af[4], bfr[4];
#pragma unroll
    for (int i = 0; i < 4; ++i) {
      af[i] = *reinterpret_cast<const bf16x8*>(&As[cur][(wr * 64 + i * 16 + lr) * 32 + hg * 8]);
      bfr[i] = *reinterpret_cast<const bf16x8*>(&Bs[cur][(wc * 64 + i * 16 + lr) * 32 + hg * 8]);
    }
    __builtin_amdgcn_s_setprio(1);
#pragma unroll
    for (int i = 0; i < 4; ++i)
#pragma unroll
      for (int j = 0; j < 4; ++j)
        acc[i][j] = __builtin_amdgcn_mfma_f32_16x16x32_bf16(af[i], bfr[j], acc[i][j], 0, 0, 0);
    __builtin_amdgcn_s_setprio(0);
    cur ^= 1;
  }

#pragma unroll
  for (int j = 0; j < 4; ++j) {
    const int col = bn * 128 + wc * 64 + j * 16 + lr;
    const float bv = bias[col];
    const int which = col >> 10;            // 0=q 1=k 2=v (uniform per wave)
    const int hh = (col >> 6) & 15;
    const int dh = col & 63;
    // q pre-scaled by SCALE * log2(e) so attention can use exp2 directly
    const float scl = which == 0 ? 0.18033688011112042f : 1.0f;
#pragma unroll
    for (int i = 0; i < 4; ++i) {
      if (which == 2) {
        const int row0 = bm * 128 + wr * 64 + i * 16 + hg * 4;   // 4 consecutive rows
        const int b = row0 >> 11, n0 = row0 & 2047;
        ushort4 vv;
        vv.x = f2bf(acc[i][j][0] + bv);
        vv.y = f2bf(acc[i][j][1] + bv);
        vv.z = f2bf(acc[i][j][2] + bv);
        vv.w = f2bf(acc[i][j][3] + bv);
        *reinterpret_cast<ushort4*>(
            &vtbuf[((size_t)((b * 16 + hh) * 64 + dh)) * 2048 + n0]) = vv;
      } else {
        unsigned short* dst = which == 0 ? qb : kbuf;
#pragma unroll
        for (int r = 0; r < 4; ++r) {
          const int row = bm * 128 + wr * 64 + i * 16 + hg * 4 + r;
          const int b = row >> 11, n = row & 2047;
          dst[((size_t)((b * 16 + hh) * 2048 + n)) * 64 + dh] = f2bf((acc[i][j][r] + bv) * scl);
        }
      }
    }
  }
}

// ---------------- Proj GEMM: out[4096][1024] fp32 = AObf @ Wproj^T + b ----------
// BM=64 x BN=128 -> 512 blocks (2/CU) for occupancy; 4 waves each own 64x32.
__global__ __launch_bounds__(256, 2) void gemm_proj_kernel(
    const unsigned short* __restrict__ A,    // [4096][1024] bf16
    const unsigned short* __restrict__ Bt,   // [1024][1024] bf16
    const float* __restrict__ bias,          // [1024]
    float* __restrict__ out) {
  __shared__ __align__(16) unsigned short As[2][64 * 32];
  __shared__ __align__(16) unsigned short Bs[2][128 * 32];
  const int tid = threadIdx.x;
  const int lane = tid & 63;
  const int wc = tid >> 6;                  // wave = output col quarter (0..3)
  // XCD swizzle: 512 blocks, 64 per XCD (8 bm x 8 bn)
  const int lin = blockIdx.y * 8 + blockIdx.x;
  const int wg = (lin & 7) * 64 + (lin >> 3);
  const int bm = wg >> 3, bn = wg & 7;
  const int lr = lane & 15, hg = lane >> 4;

  f32x4 acc[4][2] = {};
  const int r0 = tid >> 2;                  // 0..63
  const int c0 = (tid & 3) * 8;

  auto STAGE = [&](int b, int kt) {
    const unsigned short* ga0 = A + (size_t)(bm * 64 + r0) * 1024 + kt * 32 + c0;
    const unsigned short* gb0 = Bt + (size_t)(bn * 128 + r0) * 1024 + kt * 32 + c0;
    const unsigned short* gb1 = Bt + (size_t)(bn * 128 + r0 + 64) * 1024 + kt * 32 + c0;
    __builtin_amdgcn_global_load_lds((GVT*)ga0, (LVT*)&As[b][tid * 8], 16, 0, 0);
    __builtin_amdgcn_global_load_lds((GVT*)gb0, (LVT*)&Bs[b][tid * 8], 16, 0, 0);
    __builtin_amdgcn_global_load_lds((GVT*)gb1, (LVT*)&Bs[b][(tid + 256) * 8], 16, 0, 0);
  };

  STAGE(0, 0);
  int cur = 0;
  for (int kt = 0; kt < 32; ++kt) {
    __syncthreads();
    if (kt + 1 < 32) STAGE(cur ^ 1, kt + 1);
    bf16x8 af[4], bfr[2];
#pragma unroll
    for (int i = 0; i < 4; ++i)
      af[i] = *reinterpret_cast<const bf16x8*>(&As[cur][(i * 16 + lr) * 32 + hg * 8]);
#pragma unroll
    for (int j = 0; j < 2; ++j)
      bfr[j] = *reinterpret_cast<const bf16x8*>(&Bs[cur][(wc * 32 + j * 16 + lr) * 32 + hg * 8]);
    __builtin_amdgcn_s_setprio(1);
#pragma unroll
    for (int i = 0; i < 4; ++i)
#pragma unroll
      for (int j = 0; j < 2; ++j)
        acc[i][j] = __builtin_amdgcn_mfma_f32_16x16x32_bf16(af[i], bfr[j], acc[i][j], 0, 0, 0);
    __builtin_amdgcn_s_setprio(0);
    cur ^= 1;
  }

#pragma unroll
  for (int j = 0; j < 2; ++j) {
    const int col = bn * 128 + wc * 32 + j * 16 + lr;
    const float bv = bias[col];
#pragma unroll
    for (int i = 0; i < 4; ++i)
#pragma unroll
      for (int r = 0; r < 4; ++r) {
        const int row = bm * 64 + i * 16 + hg * 4 + r;
        out[(size_t)row * 1024 + col] = acc[i][j][r] + bv;
      }
  }
}

// ---------------- Flash attention: key-range split + ANTI-PHASED streams.
// Stream 0 waves: QKT(kt) -> SMPV(kt).  Stream 1 waves: SMPV(kt-1) -> QKT(kt)
// (accT carried in registers across the barrier; V triple-buffered so V(kt-1)
// survives one extra interval). Halves of each SIMD are now in opposite
// (MFMA-heavy vs trans/VALU-heavy) phases -> pipes co-run. ----------
__global__ __launch_bounds__(512, 4) void attn_kernel(
    const unsigned short* __restrict__ qb,    // [32][2048][64] bf16, pre-scaled
    const unsigned short* __restrict__ kbuf,  // [32][2048][64]
    const unsigned short* __restrict__ vt,    // [32][64][2048]  (V^T per head)
    unsigned short* __restrict__ ao) {        // [4096][1024] bf16
  // K: 2 streams x 2 bufs; V: 2 streams x 3 bufs. 80 KB total; scr overlays.
  __shared__ __align__(16) unsigned short SMEM[16384 + 24576];
  const int tid = threadIdx.x;
  const int lane = tid & 63;
  const int wid = tid >> 6;                   // 0..7
  const int ws = wid >> 2;                    // key-stream 0/1
  const int wq = wid & 3;                     // q sub-tile 0..3
  const int lr = lane & 15;
  const int hg = lane >> 4;                   // 0..3
  // XCD-bijective swizzle (512 blocks): all 16 q-tiles of a head on one XCD
  const int lin = blockIdx.y * 16 + blockIdx.x;
  const int wg = (lin & 7) * 64 + (lin >> 3);
  const int qt = wg & 15;                     // 0..15, 128 q-rows per block
  const int bh = wg >> 4;                     // 0..31
  const size_t hbase = (size_t)bh * SEQ * 64;

  // Q B-frags: this wave's 32 q-rows = qt*128 + wq*32 + m*16 + lr
  bf16x8 qf[2][2];
#pragma unroll
  for (int m = 0; m < 2; ++m) {
    const unsigned short* qp =
        qb + hbase + (size_t)(qt * 128 + wq * 32 + m * 16 + lr) * 64 + hg * 8;
    qf[m][0] = *reinterpret_cast<const bf16x8*>(qp);
    qf[m][1] = *reinterpret_cast<const bf16x8*>(qp + 32);
  }

  f32x4 accO[2][4] = {};                      // O^T: lane q=m*16+lr, d=jd*16+hg*4+r
  float l_run[2] = {0.0f, 0.0f};              // per-lane partial (hg-reduced at end)
  f32x4 accT[2][4];                           // S^T tile state (s1 carries across iters)

  const int srow = tid >> 3;                  // 0..63
  const int ssw = ((tid & 7) ^ (srow & 7)) * 8;
  auto STAGE = [&](int kt) {
#pragma unroll
    for (int s = 0; s < 2; ++s) {
      const unsigned short* gk =
          kbuf + hbase + (size_t)(s * 1024 + kt * 64 + srow) * 64 + ssw;
      __builtin_amdgcn_global_load_lds(
          (GVT*)gk, (LVT*)&SMEM[(s * 2 + (kt & 1)) * 4096 + tid * 8], 16, 0, 0);
      const unsigned short* gv =
          vt + hbase + (size_t)srow * 2048 + s * 1024 + kt * 64 + ssw;
      __builtin_amdgcn_global_load_lds(
          (GVT*)gv, (LVT*)&SMEM[16384 + (s * 3 + (kt % 3)) * 4096 + tid * 8], 16, 0, 0);
    }
  };

  const int sw0 = (hg ^ (lr & 7)) * 8;        // swizzled slot, k-chunk 0
  const int sw1 = ((hg + 4) ^ (lr & 7)) * 8;  // swizzled slot, k-chunk 1

  auto QKT = [&](int kt) {
    const unsigned short* Ksb = &SMEM[(ws * 2 + (kt & 1)) * 4096];
    __builtin_amdgcn_s_setprio(1);
#pragma unroll
    for (int j = 0; j < 4; ++j) {
      const bf16x8 kf0 = *reinterpret_cast<const bf16x8*>(&Ksb[(j * 16 + lr) * 64 + sw0]);
      const bf16x8 kf1 = *reinterpret_cast<const bf16x8*>(&Ksb[(j * 16 + lr) * 64 + sw1]);
      f32x4 z0 = {};
      z0 = __builtin_amdgcn_mfma_f32_16x16x32_bf16(kf0, qf[0][0], z0, 0, 0, 0);
      accT[0][j] = __builtin_amdgcn_mfma_f32_16x16x32_bf16(kf1, qf[0][1], z0, 0, 0, 0);
      f32x4 z1 = {};
      z1 = __builtin_amdgcn_mfma_f32_16x16x32_bf16(kf0, qf[1][0], z1, 0, 0, 0);
      accT[1][j] = __builtin_amdgcn_mfma_f32_16x16x32_bf16(kf1, qf[1][1], z1, 0, 0, 0);
    }
    __builtin_amdgcn_s_setprio(0);
  };

  auto SMPV = [&](int vb) {
    const unsigned short* Vsb = &SMEM[16384 + (ws * 3 + vb) * 4096];
    bf16x8 pB[2][2];
#pragma unroll
    for (int m = 0; m < 2; ++m) {
      unsigned w[4][2];
      float ps0 = 0.f, ps1 = 0.f;
#pragma unroll
      for (int j = 0; j < 4; ++j) {
        const float p0 = __builtin_amdgcn_exp2f(accT[m][j][0]);
        const float p1 = __builtin_amdgcn_exp2f(accT[m][j][1]);
        const float p2 = __builtin_amdgcn_exp2f(accT[m][j][2]);
        const float p3 = __builtin_amdgcn_exp2f(accT[m][j][3]);
        ps0 += (p0 + p1);
        ps1 += (p2 + p3);
        w[j][0] = pk_bf16(p0, p1);
        w[j][1] = pk_bf16(p2, p3);
      }
      l_run[m] += ps0 + ps1;
#pragma unroll
      for (int h = 0; h < 2; ++h) {
        unsigned e0 = w[2 * h][0], e1 = w[2 * h][1];
        unsigned f0 = w[2 * h + 1][0], f1 = w[2 * h + 1][1];
        asm("v_permlane32_swap_b32 %0, %1" : "+v"(e0), "+v"(f0));
        asm("v_permlane32_swap_b32 %0, %1" : "+v"(e1), "+v"(f1));
        asm("v_permlane16_swap_b32 %0, %1" : "+v"(e0), "+v"(f0));
        asm("v_permlane16_swap_b32 %0, %1" : "+v"(e1), "+v"(f1));
        const i32x4 pw = {(int)e0, (int)e1, (int)f0, (int)f1};
        pB[m][h] = __builtin_bit_cast(bf16x8, pw);
      }
    }
    __builtin_amdgcn_s_setprio(1);
#pragma unroll
    for (int jd = 0; jd < 4; ++jd) {
      const bf16x8 v0 = *reinterpret_cast<const bf16x8*>(&Vsb[(jd * 16 + lr) * 64 + sw0]);
      const bf16x8 v1 = *reinterpret_cast<const bf16x8*>(&Vsb[(jd * 16 + lr) * 64 + sw1]);
      accO[0][jd] = __builtin_amdgcn_mfma_f32_16x16x32_bf16(v0, pB[0][0], accO[0][jd], 0, 0, 0);
      accO[0][jd] = __builtin_amdgcn_mfma_f32_16x16x32_bf16(v1, pB[0][1], accO[0][jd], 0, 0, 0);
      accO[1][jd] = __builtin_amdgcn_mfma_f32_16x16x32_bf16(v0, pB[1][0], accO[1][jd], 0, 0, 0);
      accO[1][jd] = __builtin_amdgcn_mfma_f32_16x16x32_bf16(v1, pB[1][1], accO[1][jd], 0, 0, 0);
    }
    __builtin_amdgcn_s_setprio(0);
  };

  STAGE(0);
  for (int kt = 0; kt < 16; ++kt) {
    __syncthreads();                          // tile kt staged; prev reads done
    if (kt + 1 < 16) STAGE(kt + 1);
    if (ws == 0) {
      QKT(kt);
      SMPV(kt % 3);
    } else {
      if (kt > 0) SMPV((kt - 1) % 3);         // finish previous tile first
      QKT(kt);                                // then score current tile
    }
  }
  if (ws == 1) SMPV(15 % 3);                  // stream-1 tail

  // one-time cross-lane l reduction (over hg groups = lane bits 4,5)
#pragma unroll
  for (int m = 0; m < 2; ++m) {
    l_run[m] += __shfl_xor(l_run[m], 16);
    l_run[m] += __shfl_xor(l_run[m], 32);
  }

  // ---- cross-stream combine: plain sum of O and l. Scratch overlays SMEM. ----
  float* scr = (float*)&SMEM[0];              // 80 KB available, need ~38 KB
  const int sbase = (wq * 64 + lane) * 37;    // stride 37: conflict-light
  __syncthreads();                            // all tile reads done
  if (ws == 1) {
#pragma unroll
    for (int m = 0; m < 2; ++m) {
#pragma unroll
      for (int jd = 0; jd < 4; ++jd)
#pragma unroll
        for (int r = 0; r < 4; ++r) scr[sbase + m * 16 + jd * 4 + r] = accO[m][jd][r];
      scr[sbase + 32 + m] = l_run[m];
    }
  }
  __syncthreads();
  if (ws == 0) {
    const int b = bh >> 4, hh = bh & 15;
#pragma unroll
    for (int m = 0; m < 2; ++m) {
      const float inv = 1.0f / (l_run[m] + scr[sbase + 32 + m]);
      const int qrow = qt * 128 + wq * 32 + m * 16 + lr;
      unsigned short* dst = ao + (size_t)(b * 2048 + qrow) * 1024 + hh * 64;
#pragma unroll
      for (int jd = 0; jd < 4; ++jd) {
        const float o0 = (accO[m][jd][0] + scr[sbase + m * 16 + jd * 4 + 0]) * inv;
        const float o1 = (accO[m][jd][1] + scr[sbase + m * 16 + jd * 4 + 1]) * inv;
        const float o2 = (accO[m][jd][2] + scr[sbase + m * 16 + jd * 4 + 2]) * inv;
        const float o3 = (accO[m][jd][3] + scr[sbase + m * 16 + jd * 4 + 3]) * inv;
        uint2 o;
        o.x = pk_bf16(o0, o1);
        o.y = pk_bf16(o2, o3);
        *reinterpret_cast<uint2*>(dst + jd * 16 + hg * 4) = o;
      }
    }
  }
}

extern "C" void kernel_launch(void* const* d_in, const int* in_sizes, int n_in,
                              void* d_out, int out_size, void* d_ws, size_t ws_size,
                              hipStream_t stream) {
  const float* x = (const float*)d_in[0];
  const float* w_qkv = (const float*)d_in[1];
  const float* b_qkv = (const float*)d_in[2];
  const float* w_proj = (const float*)d_in[3];
  const float* b_proj = (const float*)d_in[4];
  float* out = (float*)d_out;
  char* ws = (char*)d_ws;
  unsigned short* x_bf = (unsigned short*)(ws);                   // [0, 8MB)
  unsigned short* ao_bf = (unsigned short*)(ws);                  // overlay, [0, 8MB)
  unsigned short* wq_bf = (unsigned short*)(ws + (8ull << 20));   // [8, 14MB)
  unsigned short* wp_bf = (unsigned short*)(ws + (14ull << 20));  // [14, 16MB)
  unsigned short* q_bf = (unsigned short*)(ws + (16ull << 20));   // [16, 24MB)
  unsigned short* k_bf = (unsigned short*)(ws + (24ull << 20));   // [24, 32MB)
  unsigned short* vt_bf = (unsigned short*)(ws + (32ull << 20));  // [32, 40MB)  V^T

  cvt3_kernel<<<2048, 256, 0, stream>>>(x, x_bf, 4096 * 1024 / 4,
                                        w_qkv, wq_bf, 3072 * 1024 / 4,
                                        w_proj, wp_bf, 1024 * 1024 / 4);
  gemm_qkv_kernel<<<dim3(24, 32), 256, 0, stream>>>(x_bf, wq_bf, b_qkv, q_bf, k_bf, vt_bf);
  attn_kernel<<<dim3(16, 32), 512, 0, stream>>>(q_bf, k_bf, vt_bf, ao_bf);
  gemm_proj_kernel<<<dim3(8, 64), 256, 0, stream>>>(ao_bf, wp_bf, b_proj, out);
}

// Round 15
// 111.600 us; speedup vs baseline: 1.0845x; 1.0845x over previous
//
#include <hip/hip_runtime.h>
#include <stdint.h>

#define SEQ 2048

typedef __attribute__((ext_vector_type(8))) short bf16x8;
typedef __attribute__((ext_vector_type(4))) float f32x4;
typedef __attribute__((ext_vector_type(4))) int i32x4;

typedef const __attribute__((address_space(1))) unsigned int GVT;
typedef __attribute__((address_space(3))) unsigned int LVT;

static __device__ __forceinline__ unsigned short f2bf(float f) {
  unsigned u = __builtin_bit_cast(unsigned, f);
  u += 0x7fffu + ((u >> 16) & 1u);
  return (unsigned short)(u >> 16);
}

static __device__ __forceinline__ unsigned pk_bf16(float lo, float hi) {
  unsigned r;
  asm("v_cvt_pk_bf16_f32 %0, %1, %2" : "=v"(r) : "v"(lo), "v"(hi));
  return r;
}

// one kernel converts x, w_qkv, w_proj (saves 2 launch overheads)
__global__ __launch_bounds__(256) void cvt3_kernel(
    const float* __restrict__ s0, unsigned short* __restrict__ d0, int n0,
    const float* __restrict__ s1, unsigned short* __restrict__ d1, int n1,
    const float* __restrict__ s2, unsigned short* __restrict__ d2, int n2) {
  int i = blockIdx.x * 256 + threadIdx.x;
  const int stride = gridDim.x * 256;
  const int total = n0 + n1 + n2;
  for (; i < total; i += stride) {
    const float* s;
    unsigned short* d;
    int k;
    if (i < n0) { s = s0; d = d0; k = i; }
    else if (i < n0 + n1) { s = s1; d = d1; k = i - n0; }
    else { s = s2; d = d2; k = i - n0 - n1; }
    float4 v = reinterpret_cast<const float4*>(s)[k];
    ushort4 o;
    o.x = f2bf(v.x); o.y = f2bf(v.y); o.z = f2bf(v.z); o.w = f2bf(v.w);
    reinterpret_cast<ushort4*>(d)[k] = o;
  }
}

// ---------------- QKV GEMM: C[4096][3072] = Xbf @ Wqkv^T, scatter to q/k/vt ----------
// q: [32][2048][64] (pre-scaled by SCALE*log2e); k: [32][2048][64]; vt: [32][64][2048]
__global__ __launch_bounds__(256, 3) void gemm_qkv_kernel(
    const unsigned short* __restrict__ A,    // [4096][1024] bf16
    const unsigned short* __restrict__ Bt,   // [3072][1024] bf16
    const float* __restrict__ bias,          // [3072]
    unsigned short* __restrict__ qb,
    unsigned short* __restrict__ kbuf,
    unsigned short* __restrict__ vtbuf) {
  __shared__ __align__(16) unsigned short As[2][128 * 32];
  __shared__ __align__(16) unsigned short Bs[2][128 * 32];
  const int tid = threadIdx.x;
  const int lane = tid & 63;
  const int wid = tid >> 6;
  const int wr = wid >> 1, wc = wid & 1;
  // XCD-bijective swizzle: 768 blocks, 768/8 = 96 per XCD (4 bm-rows each)
  const int lin = blockIdx.y * 24 + blockIdx.x;
  const int wg = (lin & 7) * 96 + (lin >> 3);
  const int bm = wg / 24, bn = wg % 24;
  const int lr = lane & 15, hg = lane >> 4;

  f32x4 acc[4][4] = {};

  const int r0 = tid >> 2;                 // staging row
  const int c0 = (tid & 3) * 8;            // staging col (elements)

  auto STAGE = [&](int b, int kt) {
    const unsigned short* ga0 = A + (size_t)(bm * 128 + r0) * 1024 + kt * 32 + c0;
    const unsigned short* ga1 = A + (size_t)(bm * 128 + r0 + 64) * 1024 + kt * 32 + c0;
    const unsigned short* gb0 = Bt + (size_t)(bn * 128 + r0) * 1024 + kt * 32 + c0;
    const unsigned short* gb1 = Bt + (size_t)(bn * 128 + r0 + 64) * 1024 + kt * 32 + c0;
    __builtin_amdgcn_global_load_lds((GVT*)ga0, (LVT*)&As[b][tid * 8], 16, 0, 0);
    __builtin_amdgcn_global_load_lds((GVT*)ga1, (LVT*)&As[b][(tid + 256) * 8], 16, 0, 0);
    __builtin_amdgcn_global_load_lds((GVT*)gb0, (LVT*)&Bs[b][tid * 8], 16, 0, 0);
    __builtin_amdgcn_global_load_lds((GVT*)gb1, (LVT*)&Bs[b][(tid + 256) * 8], 16, 0, 0);
  };

  STAGE(0, 0);
  int cur = 0;
  for (int kt = 0; kt < 32; ++kt) {
    __syncthreads();                       // buf[cur] staged; prev reads done
    if (kt + 1 < 32) STAGE(cur ^ 1, kt + 1);
    bf16x8 af[4], bfr[4];
#pragma unroll
    for (int i = 0; i < 4; ++i) {
      af[i] = *reinterpret_cast<const bf16x8*>(&As[cur][(wr * 64 + i * 16 + lr) * 32 + hg * 8]);
      bfr[i] = *reinterpret_cast<const bf16x8*>(&Bs[cur][(wc * 64 + i * 16 + lr) * 32 + hg * 8]);
    }
    __builtin_amdgcn_s_setprio(1);
#pragma unroll
    for (int i = 0; i < 4; ++i)
#pragma unroll
      for (int j = 0; j < 4; ++j)
        acc[i][j] = __builtin_amdgcn_mfma_f32_16x16x32_bf16(af[i], bfr[j], acc[i][j], 0, 0, 0);
    __builtin_amdgcn_s_setprio(0);
    cur ^= 1;
  }

#pragma unroll
  for (int j = 0; j < 4; ++j) {
    const int col = bn * 128 + wc * 64 + j * 16 + lr;
    const float bv = bias[col];
    const int which = col >> 10;            // 0=q 1=k 2=v (uniform per wave)
    const int hh = (col >> 6) & 15;
    const int dh = col & 63;
    // q pre-scaled by SCALE * log2(e) so attention can use exp2 directly
    const float scl = which == 0 ? 0.18033688011112042f : 1.0f;
#pragma unroll
    for (int i = 0; i < 4; ++i) {
      if (which == 2) {
        const int row0 = bm * 128 + wr * 64 + i * 16 + hg * 4;   // 4 consecutive rows
        const int b = row0 >> 11, n0 = row0 & 2047;
        ushort4 vv;
        vv.x = f2bf(acc[i][j][0] + bv);
        vv.y = f2bf(acc[i][j][1] + bv);
        vv.z = f2bf(acc[i][j][2] + bv);
        vv.w = f2bf(acc[i][j][3] + bv);
        *reinterpret_cast<ushort4*>(
            &vtbuf[((size_t)((b * 16 + hh) * 64 + dh)) * 2048 + n0]) = vv;
      } else {
        unsigned short* dst = which == 0 ? qb : kbuf;
#pragma unroll
        for (int r = 0; r < 4; ++r) {
          const int row = bm * 128 + wr * 64 + i * 16 + hg * 4 + r;
          const int b = row >> 11, n = row & 2047;
          dst[((size_t)((b * 16 + hh) * 2048 + n)) * 64 + dh] = f2bf((acc[i][j][r] + bv) * scl);
        }
      }
    }
  }
}

// ---------------- Proj GEMM: out[4096][1024] fp32 = AObf @ Wproj^T + b ----------
// BM=32 x BN=128 -> 1024 blocks (4/CU, 16 waves/CU) for latency hiding.
__global__ __launch_bounds__(256, 4) void gemm_proj_kernel(
    const unsigned short* __restrict__ A,    // [4096][1024] bf16
    const unsigned short* __restrict__ Bt,   // [1024][1024] bf16
    const float* __restrict__ bias,          // [1024]
    float* __restrict__ out) {
  __shared__ __align__(16) unsigned short As[2][32 * 32];
  __shared__ __align__(16) unsigned short Bs[2][128 * 32];
  const int tid = threadIdx.x;
  const int lane = tid & 63;
  const int wc = tid >> 6;                  // wave = output col quarter (0..3)
  // XCD swizzle: 1024 blocks, 128 per XCD (16 bm x 8 bn)
  const int lin = blockIdx.y * 8 + blockIdx.x;
  const int wg = (lin & 7) * 128 + (lin >> 3);
  const int bm = wg >> 3, bn = wg & 7;
  const int lr = lane & 15, hg = lane >> 4;

  f32x4 acc[2][2] = {};
  const int r0 = tid >> 2;                  // 0..63 (A uses 0..31)
  const int c0 = (tid & 3) * 8;

  auto STAGE = [&](int b, int kt) {
    if (tid < 128) {
      const unsigned short* ga0 = A + (size_t)(bm * 32 + r0) * 1024 + kt * 32 + c0;
      __builtin_amdgcn_global_load_lds((GVT*)ga0, (LVT*)&As[b][tid * 8], 16, 0, 0);
    }
    const unsigned short* gb0 = Bt + (size_t)(bn * 128 + r0) * 1024 + kt * 32 + c0;
    const unsigned short* gb1 = Bt + (size_t)(bn * 128 + r0 + 64) * 1024 + kt * 32 + c0;
    __builtin_amdgcn_global_load_lds((GVT*)gb0, (LVT*)&Bs[b][tid * 8], 16, 0, 0);
    __builtin_amdgcn_global_load_lds((GVT*)gb1, (LVT*)&Bs[b][(tid + 256) * 8], 16, 0, 0);
  };

  STAGE(0, 0);
  int cur = 0;
  for (int kt = 0; kt < 32; ++kt) {
    __syncthreads();
    if (kt + 1 < 32) STAGE(cur ^ 1, kt + 1);
    bf16x8 af[2], bfr[2];
#pragma unroll
    for (int i = 0; i < 2; ++i)
      af[i] = *reinterpret_cast<const bf16x8*>(&As[cur][(i * 16 + lr) * 32 + hg * 8]);
#pragma unroll
    for (int j = 0; j < 2; ++j)
      bfr[j] = *reinterpret_cast<const bf16x8*>(&Bs[cur][(wc * 32 + j * 16 + lr) * 32 + hg * 8]);
    __builtin_amdgcn_s_setprio(1);
#pragma unroll
    for (int i = 0; i < 2; ++i)
#pragma unroll
      for (int j = 0; j < 2; ++j)
        acc[i][j] = __builtin_amdgcn_mfma_f32_16x16x32_bf16(af[i], bfr[j], acc[i][j], 0, 0, 0);
    __builtin_amdgcn_s_setprio(0);
    cur ^= 1;
  }

#pragma unroll
  for (int j = 0; j < 2; ++j) {
    const int col = bn * 128 + wc * 32 + j * 16 + lr;
    const float bv = bias[col];
#pragma unroll
    for (int i = 0; i < 2; ++i)
#pragma unroll
      for (int r = 0; r < 4; ++r) {
        const int row = bm * 32 + i * 16 + hg * 4 + r;
        out[(size_t)row * 1024 + col] = acc[i][j][r] + bv;
      }
  }
}

// ---------------- Flash attention: key-range split (8 waves: 2 streams x 4 q-subtiles,
// 32 q-rows/wave), fixed-reference softmax (P = 2^S directly; l reduced across
// lanes ONCE at the end), K/V LDS dbuf+swizzle, S^T=K*Q, O^T=V^T*P^T. ----------
__global__ __launch_bounds__(512, 4) void attn_kernel(
    const unsigned short* __restrict__ qb,    // [32][2048][64] bf16, pre-scaled
    const unsigned short* __restrict__ kbuf,  // [32][2048][64]
    const unsigned short* __restrict__ vt,    // [32][64][2048]  (V^T per head)
    unsigned short* __restrict__ ao) {        // [4096][1024] bf16
  // KVbuf[kv][stream][buf][64*64] -- 64 KB; also reused as combine scratch
  __shared__ __align__(16) unsigned short KVbuf[2][2][2][4096];
  const int tid = threadIdx.x;
  const int lane = tid & 63;
  const int wid = tid >> 6;                   // 0..7
  const int ws = wid >> 2;                    // key-stream 0/1
  const int wq = wid & 3;                     // q sub-tile 0..3
  const int lr = lane & 15;
  const int hg = lane >> 4;                   // 0..3
  // XCD-bijective swizzle (512 blocks): all 16 q-tiles of a head on one XCD
  const int lin = blockIdx.y * 16 + blockIdx.x;
  const int wg = (lin & 7) * 64 + (lin >> 3);
  const int qt = wg & 15;                     // 0..15, 128 q-rows per block
  const int bh = wg >> 4;                     // 0..31
  const size_t hbase = (size_t)bh * SEQ * 64;

  // Q B-frags: this wave's 32 q-rows = qt*128 + wq*32 + m*16 + lr
  bf16x8 qf[2][2];
#pragma unroll
  for (int m = 0; m < 2; ++m) {
    const unsigned short* qp =
        qb + hbase + (size_t)(qt * 128 + wq * 32 + m * 16 + lr) * 64 + hg * 8;
    qf[m][0] = *reinterpret_cast<const bf16x8*>(qp);
    qf[m][1] = *reinterpret_cast<const bf16x8*>(qp + 32);
  }

  f32x4 accO[2][4] = {};                      // O^T: lane q=m*16+lr, d=jd*16+hg*4+r
  float l_run[2] = {0.0f, 0.0f};              // per-lane partial (hg-reduced at end)

  const int srow = tid >> 3;                  // 0..63
  const int ssw = ((tid & 7) ^ (srow & 7)) * 8;
  auto STAGE = [&](int b, int kt) {
#pragma unroll
    for (int s = 0; s < 2; ++s) {
      const unsigned short* gk =
          kbuf + hbase + (size_t)(s * 1024 + kt * 64 + srow) * 64 + ssw;
      __builtin_amdgcn_global_load_lds((GVT*)gk, (LVT*)&KVbuf[0][s][b][tid * 8], 16, 0, 0);
      const unsigned short* gv =
          vt + hbase + (size_t)srow * 2048 + s * 1024 + kt * 64 + ssw;
      __builtin_amdgcn_global_load_lds((GVT*)gv, (LVT*)&KVbuf[1][s][b][tid * 8], 16, 0, 0);
    }
  };

  STAGE(0, 0);
  int cur = 0;
  const int sw0 = (hg ^ (lr & 7)) * 8;        // swizzled slot, k-chunk 0
  const int sw1 = ((hg + 4) ^ (lr & 7)) * 8;  // swizzled slot, k-chunk 1

  for (int kt = 0; kt < 16; ++kt) {
    __syncthreads();                          // buf[cur] staged; prev-tile reads done
    if (kt + 1 < 16) STAGE(cur ^ 1, kt + 1);

    const unsigned short* Ksb = &KVbuf[0][ws][cur][0];
    const unsigned short* Vsb = &KVbuf[1][ws][cur][0];

    // S^T = K * Q : lane holds key=j*16+hg*4+r (within this stream), q=m*16+lr
    f32x4 accT[2][4] = {};
    __builtin_amdgcn_s_setprio(1);
#pragma unroll
    for (int j = 0; j < 4; ++j) {
      const bf16x8 kf0 = *reinterpret_cast<const bf16x8*>(&Ksb[(j * 16 + lr) * 64 + sw0]);
      const bf16x8 kf1 = *reinterpret_cast<const bf16x8*>(&Ksb[(j * 16 + lr) * 64 + sw1]);
      accT[0][j] = __builtin_amdgcn_mfma_f32_16x16x32_bf16(kf0, qf[0][0], accT[0][j], 0, 0, 0);
      accT[0][j] = __builtin_amdgcn_mfma_f32_16x16x32_bf16(kf1, qf[0][1], accT[0][j], 0, 0, 0);
      accT[1][j] = __builtin_amdgcn_mfma_f32_16x16x32_bf16(kf0, qf[1][0], accT[1][j], 0, 0, 0);
      accT[1][j] = __builtin_amdgcn_mfma_f32_16x16x32_bf16(kf1, qf[1][1], accT[1][j], 0, 0, 0);
    }
    __builtin_amdgcn_s_setprio(0);

    // fixed-ref softmax: P = 2^S directly; l accumulates per-lane (no shuffles here)
    bf16x8 pB[2][2];
#pragma unroll
    for (int m = 0; m < 2; ++m) {
      unsigned w[4][2];
      float ps0 = 0.f, ps1 = 0.f;
#pragma unroll
      for (int j = 0; j < 4; ++j) {
        const float p0 = __builtin_amdgcn_exp2f(accT[m][j][0]);
        const float p1 = __builtin_amdgcn_exp2f(accT[m][j][1]);
        const float p2 = __builtin_amdgcn_exp2f(accT[m][j][2]);
        const float p3 = __builtin_amdgcn_exp2f(accT[m][j][3]);
        ps0 += (p0 + p1);
        ps1 += (p2 + p3);
        w[j][0] = pk_bf16(p0, p1);
        w[j][1] = pk_bf16(p2, p3);
      }
      l_run[m] += ps0 + ps1;
#pragma unroll
      for (int h = 0; h < 2; ++h) {
        unsigned e0 = w[2 * h][0], e1 = w[2 * h][1];
        unsigned f0 = w[2 * h + 1][0], f1 = w[2 * h + 1][1];
        asm("v_permlane32_swap_b32 %0, %1" : "+v"(e0), "+v"(f0));
        asm("v_permlane32_swap_b32 %0, %1" : "+v"(e1), "+v"(f1));
        asm("v_permlane16_swap_b32 %0, %1" : "+v"(e0), "+v"(f0));
        asm("v_permlane16_swap_b32 %0, %1" : "+v"(e1), "+v"(f1));
        const i32x4 pw = {(int)e0, (int)e1, (int)f0, (int)f1};
        pB[m][h] = __builtin_bit_cast(bf16x8, pw);
      }
    }

    // PV: O^T += V^T * P^T (V frags shared across m)
    __builtin_amdgcn_s_setprio(1);
#pragma unroll
    for (int jd = 0; jd < 4; ++jd) {
      const bf16x8 v0 = *reinterpret_cast<const bf16x8*>(&Vsb[(jd * 16 + lr) * 64 + sw0]);
      const bf16x8 v1 = *reinterpret_cast<const bf16x8*>(&Vsb[(jd * 16 + lr) * 64 + sw1]);
      accO[0][jd] = __builtin_amdgcn_mfma_f32_16x16x32_bf16(v0, pB[0][0], accO[0][jd], 0, 0, 0);
      accO[0][jd] = __builtin_amdgcn_mfma_f32_16x16x32_bf16(v1, pB[0][1], accO[0][jd], 0, 0, 0);
      accO[1][jd] = __builtin_amdgcn_mfma_f32_16x16x32_bf16(v0, pB[1][0], accO[1][jd], 0, 0, 0);
      accO[1][jd] = __builtin_amdgcn_mfma_f32_16x16x32_bf16(v1, pB[1][1], accO[1][jd], 0, 0, 0);
    }
    __builtin_amdgcn_s_setprio(0);
    cur ^= 1;
  }

  // one-time cross-lane l reduction (over hg groups = lane bits 4,5)
#pragma unroll
  for (int m = 0; m < 2; ++m) {
    l_run[m] += __shfl_xor(l_run[m], 16);
    l_run[m] += __shfl_xor(l_run[m], 32);
  }

  // ---- cross-stream combine: plain sum of O and l. Scratch overlays K/V LDS. ----
  float* scr = (float*)&KVbuf[0][0][0][0];    // 64 KB available
  const int sbase = (wq * 64 + lane) * 37;    // stride 37: conflict-light
  __syncthreads();                            // all tile reads done
  if (ws == 1) {
#pragma unroll
    for (int m = 0; m < 2; ++m) {
#pragma unroll
      for (int jd = 0; jd < 4; ++jd)
#pragma unroll
        for (int r = 0; r < 4; ++r) scr[sbase + m * 16 + jd * 4 + r] = accO[m][jd][r];
      scr[sbase + 32 + m] = l_run[m];
    }
  }
  __syncthreads();
  if (ws == 0) {
    const int b = bh >> 4, hh = bh & 15;
#pragma unroll
    for (int m = 0; m < 2; ++m) {
      const float inv = 1.0f / (l_run[m] + scr[sbase + 32 + m]);
      const int qrow = qt * 128 + wq * 32 + m * 16 + lr;
      unsigned short* dst = ao + (size_t)(b * 2048 + qrow) * 1024 + hh * 64;
#pragma unroll
      for (int jd = 0; jd < 4; ++jd) {
        const float o0 = (accO[m][jd][0] + scr[sbase + m * 16 + jd * 4 + 0]) * inv;
        const float o1 = (accO[m][jd][1] + scr[sbase + m * 16 + jd * 4 + 1]) * inv;
        const float o2 = (accO[m][jd][2] + scr[sbase + m * 16 + jd * 4 + 2]) * inv;
        const float o3 = (accO[m][jd][3] + scr[sbase + m * 16 + jd * 4 + 3]) * inv;
        uint2 o;
        o.x = pk_bf16(o0, o1);
        o.y = pk_bf16(o2, o3);
        *reinterpret_cast<uint2*>(dst + jd * 16 + hg * 4) = o;
      }
    }
  }
}

extern "C" void kernel_launch(void* const* d_in, const int* in_sizes, int n_in,
                              void* d_out, int out_size, void* d_ws, size_t ws_size,
                              hipStream_t stream) {
  const float* x = (const float*)d_in[0];
  const float* w_qkv = (const float*)d_in[1];
  const float* b_qkv = (const float*)d_in[2];
  const float* w_proj = (const float*)d_in[3];
  const float* b_proj = (const float*)d_in[4];
  float* out = (float*)d_out;
  char* ws = (char*)d_ws;
  unsigned short* x_bf = (unsigned short*)(ws);                   // [0, 8MB)
  unsigned short* ao_bf = (unsigned short*)(ws);                  // overlay, [0, 8MB)
  unsigned short* wq_bf = (unsigned short*)(ws + (8ull << 20));   // [8, 14MB)
  unsigned short* wp_bf = (unsigned short*)(ws + (14ull << 20));  // [14, 16MB)
  unsigned short* q_bf = (unsigned short*)(ws + (16ull << 20));   // [16, 24MB)
  unsigned short* k_bf = (unsigned short*)(ws + (24ull << 20));   // [24, 32MB)
  unsigned short* vt_bf = (unsigned short*)(ws + (32ull << 20));  // [32, 40MB)  V^T

  cvt3_kernel<<<2048, 256, 0, stream>>>(x, x_bf, 4096 * 1024 / 4,
                                        w_qkv, wq_bf, 3072 * 1024 / 4,
                                        w_proj, wp_bf, 1024 * 1024 / 4);
  gemm_qkv_kernel<<<dim3(24, 32), 256, 0, stream>>>(x_bf, wq_bf, b_qkv, q_bf, k_bf, vt_bf);
  attn_kernel<<<dim3(16, 32), 512, 0, stream>>>(q_bf, k_bf, vt_bf, ao_bf);
  gemm_proj_kernel<<<dim3(8, 128), 256, 0, stream>>>(ao_bf, wp_bf, b_proj, out);
}